// Round 2
// baseline (354.424 us; speedup 1.0000x reference)
//
#include <hip/hip_runtime.h>

// ModConv2D — StyleGAN2 modulated conv as implicit GEMM, f16 MFMA.
// B=16, H=W=64, CIN=COUT=256, 3x3 SAME, fp32 I/O.
//
// R6 (resubmit — previous run was an infra failure, source unchanged):
//     (a) prologue fused: prep computes Wt transpose AND scale2 partials
//     (scale2 = sum_ci st^2 * sum_t kern^2, exact fp32) — modscale_part gone,
//     kern read once instead of 17x.
//     (b) gemm: raw s_barrier + lgkmcnt(0) (no vmcnt drain) + next-slice x
//     prefetch into registers spanning the barriers (T14).
//     (c) BPITCH 100->104: bf LDS reads 4-way -> 2-way bank aliasing.
//     (d) XCD-aware block swizzle: both n-halves + halo-sharing mtiles of an
//     image land on one XCD's L2.

#define HH 64
#define WW 64
#define CI 256
#define CO 256
#define KTOT 2304
#define CIPITCH 40       // ushorts per (row,col): 32 ci + 8 pad (80 B, 2-way banks)
#define XCOLS 66
#define BPITCH 104       // ushorts per co row in bs: 96 k + 8 pad (208 B, 2-way banks)

typedef float    f32x4 __attribute__((ext_vector_type(4)));
typedef _Float16 f16x8 __attribute__((ext_vector_type(8)));
typedef __fp16   fp16x2 __attribute__((ext_vector_type(2)));

__device__ __forceinline__ unsigned pk2(float a, float b) {
    fp16x2 h = __builtin_amdgcn_cvt_pkrtz(a, b);
    return __builtin_bit_cast(unsigned, h);
}

// Raw barrier: drain LDS ops (cross-wave visibility) but NOT vmcnt — lets
// register-destined global prefetches stay in flight across the barrier.
#define BAR() do { \
    asm volatile("s_waitcnt lgkmcnt(0)" ::: "memory"); \
    __builtin_amdgcn_s_barrier(); \
} while (0)

// ---- fused prep: Wt[co][k] transpose+f16  AND  scale2 partial sums ----
// scale2[b][co] = sum_{t,ci} kern[t][ci][co]^2 * (style[b][ci]+1)^2
// Block (kt,ct): k0=kt*64 (one tap, 64 ci), c0=ct*64. Each block adds its
// 64-ci partial for 16 b x 64 co via atomicAdd (scale2 pre-zeroed).
__global__ __launch_bounds__(256) void prep(
    const float* __restrict__ kern,    // [9][CI][CO]
    const float* __restrict__ style,   // [B][CI]
    ushort* __restrict__ Wt,           // [CO][KTOT]
    float* __restrict__ scale2)        // [B][CO], pre-zeroed
{
    __shared__ ushort tile[64][65];
    __shared__ float  sqt[64][65];
    __shared__ float  st2l[16][64];

    const int kt = blockIdx.x >> 2;     // 0..35
    const int ct = blockIdx.x & 3;
    const int k0 = kt * 64, c0 = ct * 64;
    const int ci0 = k0 & 255;
    const int tid = threadIdx.x;
    const int r = tid >> 2, q = tid & 3;

    // (style+1)^2 for this block's 64-ci window, all 16 samples
    #pragma unroll
    for (int p = 0; p < 4; ++p) {
        const int i = p * 256 + tid;            // 0..1023
        const int bb = i >> 6, rr = i & 63;
        const float s = style[bb * CI + ci0 + rr] + 1.0f;
        st2l[bb][rr] = s * s;
    }

    const float* src = kern + (size_t)(k0 + r) * CO + c0 + q * 16;
    #pragma unroll
    for (int j = 0; j < 16; ++j) {
        const float v = src[j];
        _Float16 h = (_Float16)v;
        tile[q * 16 + j][r] = __builtin_bit_cast(unsigned short, h);
        sqt[r][q * 16 + j] = v * v;             // fp32 squares for demod
    }
    __syncthreads();

    ushort* dst = Wt + (size_t)(c0 + r) * KTOT + k0 + q * 16;
    #pragma unroll
    for (int j = 0; j < 16; ++j) dst[j] = tile[r][q * 16 + j];

    // reduce over the 64 ci: thread = (co = tid&63, 4 b's)
    const int co = tid & 63;
    const int bq = tid >> 6;                    // wave-uniform
    float acc[4] = {0.f, 0.f, 0.f, 0.f};
    #pragma unroll 4
    for (int rr = 0; rr < 64; ++rr) {
        const float s = sqt[rr][co];
        #pragma unroll
        for (int bb = 0; bb < 4; ++bb)
            acc[bb] += s * st2l[bq * 4 + bb][rr];   // broadcast read
    }
    #pragma unroll
    for (int bb = 0; bb < 4; ++bb)
        atomicAdd(&scale2[(bq * 4 + bb) * CO + c0 + co], acc[bb]);
}

// ---- implicit-GEMM conv ----
__global__ __launch_bounds__(256, 3) void gemm_conv(
    const float* __restrict__ x,        // [B][H][W][CI] fp32
    const ushort* __restrict__ Wt,      // [CO][KTOT] f16
    const float* __restrict__ style,    // [B][CI]
    const float* __restrict__ scale2,   // [B][CO] sum-of-squares
    float* __restrict__ y)              // [B][H][W][CO] fp32
{
    __shared__ __align__(16) ushort xs[4 * XCOLS * CIPITCH];  // 21120 B
    __shared__ __align__(16) ushort bs[128 * BPITCH];         // 26624 B
    __shared__ float s_style[CI];

    const int tid  = threadIdx.x;
    const int lane = tid & 63;
    const int wave = tid >> 6;

    // XCD swizzle: 1024 wgs, 8 XCDs -> each XCD gets 128 consecutive nbid
    // = 64 consecutive mtiles (2 full images) incl. both n-halves.
    const int nbid  = ((blockIdx.x & 7) << 7) | (blockIdx.x >> 3);
    const int mtile = nbid >> 1;
    const int n0    = (nbid & 1) * 128;
    const int p0    = mtile * 128;            // 2 image rows of one sample
    const int b     = p0 >> 12;
    const int h0    = (p0 >> 6) & 63;

    s_style[tid] = style[b * CI + tid] + 1.0f;

    const int wm = (wave & 1) * 64;
    const int wn = (wave >> 1) * 64;
    const int fr = lane & 15;
    const int fq = lane >> 4;
    const int xlane = fr * CIPITCH + fq * 8;   // per-lane A-frag offset

    // per-thread x staging geometry: 9 tasks (task = p*256+tid < 2112)
    int xoff[9];
    #pragma unroll
    for (int p = 0; p < 9; ++p) {
        const int task = p * 256 + tid;
        const int rowcol = task >> 3;        // 0..263
        const int chunk  = task & 7;
        const int row = rowcol / XCOLS;
        const int col = rowcol - row * XCOLS;
        const int rg = h0 - 1 + row;
        const int cg = col - 1;
        xoff[p] = ((unsigned)rg < 64u && (unsigned)cg < 64u && task < 2112)
                  ? (((b * HH + rg) * WW + cg) * CI + chunk * 4) : -1;
    }

    f32x4 acc[4][4] = {};
    f32x4 xv[9];

    // prefetch slice 0 into registers
    #pragma unroll
    for (int p = 0; p < 9; ++p) {
        f32x4 v = {0.f, 0.f, 0.f, 0.f};
        if (xoff[p] >= 0) v = *(const f32x4*)(x + xoff[p]);
        xv[p] = v;
    }

    for (int c = 0; c < 8; ++c) {
        BAR();   // prev slice's xs/bs readers done (also s_style for c=0)

        // ---- write xs from prefetched regs: modulate + f16 pack ----
        #pragma unroll
        for (int p = 0; p < 9; ++p) {
            const int task = p * 256 + tid;
            if (task < 2112) {
                const int rowcol = task >> 3;
                const int chunk  = task & 7;
                const f32x4 st = *(const f32x4*)(s_style + c * 32 + chunk * 4);
                const f32x4 m = xv[p] * st;
                uint2 u;
                u.x = pk2(m.x, m.y);
                u.y = pk2(m.z, m.w);
                *(uint2*)(xs + rowcol * CIPITCH + chunk * 4) = u;
            }
        }

        // ---- issue next slice's x loads: in flight across all barriers ----
        if (c < 7) {
            #pragma unroll
            for (int p = 0; p < 9; ++p) {
                f32x4 v = {0.f, 0.f, 0.f, 0.f};
                if (xoff[p] >= 0) v = *(const f32x4*)(x + xoff[p] + (c + 1) * 32);
                xv[p] = v;
            }
        }

        #pragma unroll
        for (int tr = 0; tr < 3; ++tr) {
            if (tr) BAR();   // prev tr's bs readers done

            // ---- stage bs: 128 co x 3 taps x 32 k ----
            #pragma unroll
            for (int p = 0; p < 6; ++p) {
                const int task = p * 256 + tid;      // < 1536
                const int co = task / 12;
                const int r  = task - co * 12;
                const int tl = r >> 2;
                const int ch = r & 3;
                const uint4 v = *(const uint4*)(Wt + (size_t)(n0 + co) * KTOT
                                                + (tr * 3 + tl) * 256 + c * 32 + ch * 8);
                *(uint4*)(bs + co * BPITCH + tl * 32 + ch * 8) = v;
            }
            BAR();           // xs (tr==0) + bs visible

            #pragma unroll
            for (int tl = 0; tl < 3; ++tl) {
                const int t  = tr * 3 + tl;
                const int dh = t / 3;                // 0..2
                const int dw = t - dh * 3;           // 0..2

                f16x8 af[4], bf[4];
                #pragma unroll
                for (int i = 0; i < 4; ++i) {
                    const int mb   = wm + i * 16;
                    const int mrow = (mb >> 6) + dh;
                    const int mcol = (mb & 63) + dw;
                    af[i] = *(const f16x8*)(xs + (mrow * XCOLS + mcol) * CIPITCH + xlane);
                }
                #pragma unroll
                for (int j = 0; j < 4; ++j)
                    bf[j] = *(const f16x8*)(bs + (wn + j * 16 + fr) * BPITCH
                                            + tl * 32 + fq * 8);
                #pragma unroll
                for (int i = 0; i < 4; ++i)
                    #pragma unroll
                    for (int j = 0; j < 4; ++j)
                        acc[i][j] = __builtin_amdgcn_mfma_f32_16x16x32_f16(
                            af[i], bf[j], acc[i][j], 0, 0, 0);
            }
        }
    }

    // ---- epilogue: demod scale + store. D: col=lane&15, row=(lane>>4)*4+reg ----
    float sc[4];
    #pragma unroll
    for (int j = 0; j < 4; ++j)
        sc[j] = __frsqrt_rn(scale2[b * CO + n0 + wn + j * 16 + fr] + 1e-8f);
    #pragma unroll
    for (int i = 0; i < 4; ++i) {
        const int m_base = p0 + wm + i * 16 + fq * 4;
        #pragma unroll
        for (int j = 0; j < 4; ++j) {
            float* yp = y + (size_t)m_base * CO + n0 + wn + j * 16 + fr;
            #pragma unroll
            for (int r = 0; r < 4; ++r)
                yp[(size_t)r * CO] = acc[i][j][r] * sc[j];
        }
    }
}

extern "C" void kernel_launch(void* const* d_in, const int* in_sizes, int n_in,
                              void* d_out, int out_size, void* d_ws, size_t ws_size,
                              hipStream_t stream) {
    const float* x     = (const float*)d_in[0];  // [16,64,64,256]
    const float* style = (const float*)d_in[1];  // [16,256]
    const float* kern  = (const float*)d_in[2];  // [3,3,256,256]
    float* out = (float*)d_out;                  // [16,64,64,256]

    float*  scale2 = (float*)d_ws;                        // 16*256 fp32 = 16 KB
    ushort* Wt     = (ushort*)((char*)d_ws + 16384);      // [256][2304] f16

    hipMemsetAsync(scale2, 0, 16 * CO * sizeof(float), stream);
    prep<<<144, 256, 0, stream>>>(kern, style, Wt, scale2);
    gemm_conv<<<512 * 2, 256, 0, stream>>>(x, Wt, style, scale2, out);
}

// Round 3
// 313.056 us; speedup vs baseline: 1.1321x; 1.1321x over previous
//
#include <hip/hip_runtime.h>

// ModConv2D — StyleGAN2 modulated conv as implicit GEMM, f16 MFMA.
// B=16, H=W=64, CIN=COUT=256, 3x3 SAME, fp32 I/O.
//
// R7: recovery + full pipeline.
//   KEEP from R6: fused prep (Wt transpose + scale2 in one kernel),
//     raw lgkmcnt-only barriers, next-slice x prefetch into registers.
//   REVERT from R6 (the poisons): __launch_bounds__(256,3) — forced VGPR 84,
//     spilled xv to scratch (+173 MB HBM, 2x slowdown); XCD swizzle (L2
//     thrash candidate); BPITCH 104 (bank conflicts rose 8.9M->12.1M).
//   NEW: bs (weight) register prefetch — next tr-phase's 6 uint4 loads fly
//     during the current 48-MFMA phase, so no phase waits on L2 latency.
//     s_setprio(1) around MFMA cluster (3 independent blocks/CU arbitrate).

#define HH 64
#define WW 64
#define CI 256
#define CO 256
#define KTOT 2304
#define CIPITCH 40       // ushorts per (row,col): 32 ci + 8 pad (80 B)
#define XCOLS 66
#define BPITCH 100       // ushorts per co row in bs: 96 k + 4 pad (200 B)

typedef float    f32x4 __attribute__((ext_vector_type(4)));
typedef _Float16 f16x8 __attribute__((ext_vector_type(8)));
typedef __fp16   fp16x2 __attribute__((ext_vector_type(2)));

__device__ __forceinline__ unsigned pk2(float a, float b) {
    fp16x2 h = __builtin_amdgcn_cvt_pkrtz(a, b);
    return __builtin_bit_cast(unsigned, h);
}

// Raw barrier: drain LDS ops (cross-wave visibility) but NOT vmcnt — lets
// register-destined global prefetches stay in flight across the barrier.
#define BAR() do { \
    asm volatile("s_waitcnt lgkmcnt(0)" ::: "memory"); \
    __builtin_amdgcn_s_barrier(); \
} while (0)

// ---- fused prep: Wt[co][k] transpose+f16  AND  scale2 partial sums ----
// scale2[b][co] = sum_{t,ci} kern[t][ci][co]^2 * (style[b][ci]+1)^2
__global__ __launch_bounds__(256) void prep(
    const float* __restrict__ kern,    // [9][CI][CO]
    const float* __restrict__ style,   // [B][CI]
    ushort* __restrict__ Wt,           // [CO][KTOT]
    float* __restrict__ scale2)        // [B][CO], pre-zeroed
{
    __shared__ ushort tile[64][65];
    __shared__ float  sqt[64][65];
    __shared__ float  st2l[16][64];

    const int kt = blockIdx.x >> 2;     // 0..35
    const int ct = blockIdx.x & 3;
    const int k0 = kt * 64, c0 = ct * 64;
    const int ci0 = k0 & 255;
    const int tid = threadIdx.x;
    const int r = tid >> 2, q = tid & 3;

    #pragma unroll
    for (int p = 0; p < 4; ++p) {
        const int i = p * 256 + tid;            // 0..1023
        const int bb = i >> 6, rr = i & 63;
        const float s = style[bb * CI + ci0 + rr] + 1.0f;
        st2l[bb][rr] = s * s;
    }

    const float* src = kern + (size_t)(k0 + r) * CO + c0 + q * 16;
    #pragma unroll
    for (int j = 0; j < 16; ++j) {
        const float v = src[j];
        _Float16 h = (_Float16)v;
        tile[q * 16 + j][r] = __builtin_bit_cast(unsigned short, h);
        sqt[r][q * 16 + j] = v * v;             // fp32 squares for demod
    }
    __syncthreads();

    ushort* dst = Wt + (size_t)(c0 + r) * KTOT + k0 + q * 16;
    #pragma unroll
    for (int j = 0; j < 16; ++j) dst[j] = tile[r][q * 16 + j];

    const int co = tid & 63;
    const int bq = tid >> 6;                    // wave-uniform
    float acc[4] = {0.f, 0.f, 0.f, 0.f};
    #pragma unroll 4
    for (int rr = 0; rr < 64; ++rr) {
        const float s = sqt[rr][co];
        #pragma unroll
        for (int bb = 0; bb < 4; ++bb)
            acc[bb] += s * st2l[bq * 4 + bb][rr];   // broadcast read
    }
    #pragma unroll
    for (int bb = 0; bb < 4; ++bb)
        atomicAdd(&scale2[(bq * 4 + bb) * CO + c0 + co], acc[bb]);
}

// ---- implicit-GEMM conv ----
__global__ __launch_bounds__(256) void gemm_conv(
    const float* __restrict__ x,        // [B][H][W][CI] fp32
    const ushort* __restrict__ Wt,      // [CO][KTOT] f16
    const float* __restrict__ style,    // [B][CI]
    const float* __restrict__ scale2,   // [B][CO] sum-of-squares
    float* __restrict__ y)              // [B][H][W][CO] fp32
{
    __shared__ __align__(16) ushort xs[4 * XCOLS * CIPITCH];  // 21120 B
    __shared__ __align__(16) ushort bs[128 * BPITCH];         // 25600 B
    __shared__ float s_style[CI];

    const int tid  = threadIdx.x;
    const int lane = tid & 63;
    const int wave = tid >> 6;

    const int mtile = blockIdx.x >> 1;
    const int n0    = (blockIdx.x & 1) * 128;
    const int p0    = mtile * 128;            // 2 image rows of one sample
    const int b     = p0 >> 12;
    const int h0    = (p0 >> 6) & 63;

    s_style[tid] = style[b * CI + tid] + 1.0f;

    const int wm = (wave & 1) * 64;
    const int wn = (wave >> 1) * 64;
    const int fr = lane & 15;
    const int fq = lane >> 4;
    const int xlane = fr * CIPITCH + fq * 8;   // per-lane A-frag offset

    // per-thread x staging geometry: 9 tasks (task = p*256+tid < 2112)
    int xoff[9];
    #pragma unroll
    for (int p = 0; p < 9; ++p) {
        const int task = p * 256 + tid;
        const int rowcol = task >> 3;        // 0..263
        const int chunk  = task & 7;
        const int row = rowcol / XCOLS;
        const int col = rowcol - row * XCOLS;
        const int rg = h0 - 1 + row;
        const int cg = col - 1;
        xoff[p] = ((unsigned)rg < 64u && (unsigned)cg < 64u && task < 2112)
                  ? (((b * HH + rg) * WW + cg) * CI + chunk * 4) : -1;
    }

    // per-thread bs staging geometry: 6 tasks (task = p*256+tid < 1536)
    int bco[6], btl[6], bch[6];
    #pragma unroll
    for (int p = 0; p < 6; ++p) {
        const int task = p * 256 + tid;
        bco[p] = task / 12;
        const int rr = task - bco[p] * 12;
        btl[p] = rr >> 2;
        bch[p] = rr & 3;
    }

    f32x4 acc[4][4] = {};
    f32x4 xv[9];
    uint4 bv[6];

    // prefetch slice 0 x and (c=0,tr=0) weights
    #pragma unroll
    for (int p = 0; p < 9; ++p) {
        f32x4 v = {0.f, 0.f, 0.f, 0.f};
        if (xoff[p] >= 0) v = *(const f32x4*)(x + xoff[p]);
        xv[p] = v;
    }
    #pragma unroll
    for (int p = 0; p < 6; ++p)
        bv[p] = *(const uint4*)(Wt + (size_t)(n0 + bco[p]) * KTOT
                                + btl[p] * 256 + bch[p] * 8);

    for (int c = 0; c < 8; ++c) {
        BAR();   // prev slice's xs/bs readers done (also s_style for c=0)

        // ---- write xs from prefetched regs: modulate + f16 pack ----
        #pragma unroll
        for (int p = 0; p < 9; ++p) {
            const int task = p * 256 + tid;
            if (task < 2112) {
                const int rowcol = task >> 3;
                const int chunk  = task & 7;
                const f32x4 st = *(const f32x4*)(s_style + c * 32 + chunk * 4);
                const f32x4 m = xv[p] * st;
                uint2 u;
                u.x = pk2(m.x, m.y);
                u.y = pk2(m.z, m.w);
                *(uint2*)(xs + rowcol * CIPITCH + chunk * 4) = u;
            }
        }

        // ---- issue next slice's x loads: fly across all barriers ----
        if (c < 7) {
            #pragma unroll
            for (int p = 0; p < 9; ++p) {
                f32x4 v = {0.f, 0.f, 0.f, 0.f};
                if (xoff[p] >= 0) v = *(const f32x4*)(x + xoff[p] + (c + 1) * 32);
                xv[p] = v;
            }
        }

        #pragma unroll
        for (int tr = 0; tr < 3; ++tr) {
            if (tr) BAR();   // prev tr's bs readers done

            // ---- write bs from prefetched bv regs ----
            #pragma unroll
            for (int p = 0; p < 6; ++p)
                *(uint4*)(bs + bco[p] * BPITCH + btl[p] * 32 + bch[p] * 8) = bv[p];
            BAR();           // xs (tr==0) + bs visible

            // ---- issue next phase's weight loads (fly under the MFMAs) ----
            if (!(c == 7 && tr == 2)) {
                const int cn  = (tr == 2) ? c + 1 : c;
                const int trn = (tr == 2) ? 0 : tr + 1;
                #pragma unroll
                for (int p = 0; p < 6; ++p)
                    bv[p] = *(const uint4*)(Wt + (size_t)(n0 + bco[p]) * KTOT
                                            + (trn * 3 + btl[p]) * 256 + cn * 32
                                            + bch[p] * 8);
            }

            __builtin_amdgcn_s_setprio(1);
            #pragma unroll
            for (int tl = 0; tl < 3; ++tl) {
                const int t  = tr * 3 + tl;
                const int dh = t / 3;                // 0..2
                const int dw = t - dh * 3;           // 0..2

                f16x8 af[4], bf[4];
                #pragma unroll
                for (int i = 0; i < 4; ++i) {
                    const int mb   = wm + i * 16;
                    const int mrow = (mb >> 6) + dh;
                    const int mcol = (mb & 63) + dw;
                    af[i] = *(const f16x8*)(xs + (mrow * XCOLS + mcol) * CIPITCH + xlane);
                }
                #pragma unroll
                for (int j = 0; j < 4; ++j)
                    bf[j] = *(const f16x8*)(bs + (wn + j * 16 + fr) * BPITCH
                                            + tl * 32 + fq * 8);
                #pragma unroll
                for (int i = 0; i < 4; ++i)
                    #pragma unroll
                    for (int j = 0; j < 4; ++j)
                        acc[i][j] = __builtin_amdgcn_mfma_f32_16x16x32_f16(
                            af[i], bf[j], acc[i][j], 0, 0, 0);
            }
            __builtin_amdgcn_s_setprio(0);
        }
    }

    // ---- epilogue: demod scale + store. D: col=lane&15, row=(lane>>4)*4+reg ----
    float sc[4];
    #pragma unroll
    for (int j = 0; j < 4; ++j)
        sc[j] = __frsqrt_rn(scale2[b * CO + n0 + wn + j * 16 + fr] + 1e-8f);
    #pragma unroll
    for (int i = 0; i < 4; ++i) {
        const int m_base = p0 + wm + i * 16 + fq * 4;
        #pragma unroll
        for (int j = 0; j < 4; ++j) {
            float* yp = y + (size_t)m_base * CO + n0 + wn + j * 16 + fr;
            #pragma unroll
            for (int r = 0; r < 4; ++r)
                yp[(size_t)r * CO] = acc[i][j][r] * sc[j];
        }
    }
}

extern "C" void kernel_launch(void* const* d_in, const int* in_sizes, int n_in,
                              void* d_out, int out_size, void* d_ws, size_t ws_size,
                              hipStream_t stream) {
    const float* x     = (const float*)d_in[0];  // [16,64,64,256]
    const float* style = (const float*)d_in[1];  // [16,256]
    const float* kern  = (const float*)d_in[2];  // [3,3,256,256]
    float* out = (float*)d_out;                  // [16,64,64,256]

    float*  scale2 = (float*)d_ws;                        // 16*256 fp32 = 16 KB
    ushort* Wt     = (ushort*)((char*)d_ws + 16384);      // [256][2304] f16

    hipMemsetAsync(scale2, 0, 16 * CO * sizeof(float), stream);
    prep<<<144, 256, 0, stream>>>(kern, style, Wt, scale2);
    gemm_conv<<<512 * 2, 256, 0, stream>>>(x, Wt, style, scale2, out);
}

// Round 4
// 235.592 us; speedup vs baseline: 1.5044x; 1.3288x over previous
//
#include <hip/hip_runtime.h>

// ModConv2D — StyleGAN2 modulated conv as implicit GEMM, f16 MFMA.
// B=16, H=W=64, CIN=COUT=256, 3x3 SAME, fp32 I/O.
//
// R8: R5's gemm_conv VERBATIM (known-good: 151 us, VGPR 104, no spill,
//     WRITE == output size) + fused prep from R6/R7 (proven correct twice:
//     Wt transpose + scale2 in one kernel, kern read once instead of 17x,
//     modscale_part dispatch eliminated).
//   Lesson from R6/R7: register prefetch (xv[9]+bv[6], ~60 live VGPRs across
//     barriers) forces spills at any allocator setting tried (84 and 132
//     VGPR both spilled; WRITE_SIZE inflated 2-3x). Do not re-add without a
//     pressure budget. Hoisted address arrays cost ~27 more regs — recompute
//     instead.

#define HH 64
#define WW 64
#define CI 256
#define CO 256
#define KTOT 2304
#define CIPITCH 40       // ushorts per (row,col): 32 ci + 8 pad (80 B -> <=2-way banks)
#define XCOLS 66
#define BPITCH 100       // ushorts per co row in bs: 96 k + 4 pad (200 B)

typedef float    f32x4 __attribute__((ext_vector_type(4)));
typedef _Float16 f16x8 __attribute__((ext_vector_type(8)));
typedef __fp16   fp16x2 __attribute__((ext_vector_type(2)));

__device__ __forceinline__ unsigned pk2(float a, float b) {
    fp16x2 h = __builtin_amdgcn_cvt_pkrtz(a, b);
    return __builtin_bit_cast(unsigned, h);
}

// ---- fused prep: Wt[co][k] transpose+f16  AND  scale2 partial sums ----
// scale2[b][co] = sum_{t,ci} kern[t][ci][co]^2 * (style[b][ci]+1)^2
// Block (kt,ct): k0=kt*64 (one tap, 64 ci), c0=ct*64. Each block adds its
// 64-ci partial for 16 b x 64 co via atomicAdd (scale2 pre-zeroed).
__global__ __launch_bounds__(256) void prep(
    const float* __restrict__ kern,    // [9][CI][CO]
    const float* __restrict__ style,   // [B][CI]
    ushort* __restrict__ Wt,           // [CO][KTOT]
    float* __restrict__ scale2)        // [B][CO], pre-zeroed
{
    __shared__ ushort tile[64][65];
    __shared__ float  sqt[64][65];
    __shared__ float  st2l[16][64];

    const int kt = blockIdx.x >> 2;     // 0..35
    const int ct = blockIdx.x & 3;
    const int k0 = kt * 64, c0 = ct * 64;
    const int ci0 = k0 & 255;
    const int tid = threadIdx.x;
    const int r = tid >> 2, q = tid & 3;

    // (style+1)^2 for this block's 64-ci window, all 16 samples
    #pragma unroll
    for (int p = 0; p < 4; ++p) {
        const int i = p * 256 + tid;            // 0..1023
        const int bb = i >> 6, rr = i & 63;
        const float s = style[bb * CI + ci0 + rr] + 1.0f;
        st2l[bb][rr] = s * s;
    }

    const float* src = kern + (size_t)(k0 + r) * CO + c0 + q * 16;
    #pragma unroll
    for (int j = 0; j < 16; ++j) {
        const float v = src[j];
        _Float16 h = (_Float16)v;
        tile[q * 16 + j][r] = __builtin_bit_cast(unsigned short, h);
        sqt[r][q * 16 + j] = v * v;             // fp32 squares for demod
    }
    __syncthreads();

    ushort* dst = Wt + (size_t)(c0 + r) * KTOT + k0 + q * 16;
    #pragma unroll
    for (int j = 0; j < 16; ++j) dst[j] = tile[r][q * 16 + j];

    // reduce over the 64 ci: thread = (co = tid&63, 4 b's)
    const int co = tid & 63;
    const int bq = tid >> 6;                    // wave-uniform
    float acc[4] = {0.f, 0.f, 0.f, 0.f};
    #pragma unroll 4
    for (int rr = 0; rr < 64; ++rr) {
        const float s = sqt[rr][co];
        #pragma unroll
        for (int bb = 0; bb < 4; ++bb)
            acc[bb] += s * st2l[bq * 4 + bb][rr];   // broadcast read
    }
    #pragma unroll
    for (int bb = 0; bb < 4; ++bb)
        atomicAdd(&scale2[(bq * 4 + bb) * CO + c0 + co], acc[bb]);
}

// ---- implicit-GEMM conv (R5 verbatim) ----
__global__ __launch_bounds__(256) void gemm_conv(
    const float* __restrict__ x,        // [B][H][W][CI] fp32
    const ushort* __restrict__ Wt,      // [CO][KTOT] f16
    const float* __restrict__ style,    // [B][CI]
    const float* __restrict__ scale2,   // [B][CO] sum-of-squares
    float* __restrict__ y)              // [B][H][W][CO] fp32
{
    __shared__ __align__(16) ushort xs[4 * XCOLS * CIPITCH];  // 21120 B
    __shared__ __align__(16) ushort bs[128 * BPITCH];         // 25600 B
    __shared__ float s_style[CI];

    const int tid  = threadIdx.x;
    const int lane = tid & 63;
    const int wave = tid >> 6;

    const int mtile = blockIdx.x >> 1;
    const int n0    = (blockIdx.x & 1) * 128;
    const int p0    = mtile * 128;            // 2 image rows of one sample
    const int b     = p0 >> 12;
    const int h0    = (p0 >> 6) & 63;

    s_style[tid] = style[b * CI + tid] + 1.0f;

    const int wm = (wave & 1) * 64;
    const int wn = (wave >> 1) * 64;
    const int fr = lane & 15;
    const int fq = lane >> 4;
    const int xlane = fr * CIPITCH + fq * 8;   // per-lane A-frag offset

    f32x4 acc[4][4] = {};

    for (int c = 0; c < 8; ++c) {
        __syncthreads();   // previous slice's xs/bs readers done (also style for c=0)

        // ---- stage xs: 4 rows x 66 cols x 32 ci, modulated, f16 ----
        #pragma unroll
        for (int p = 0; p < 9; ++p) {
            const int task = p * 256 + tid;
            if (task < 2112) {
                const int rowcol = task >> 3;        // 0..263
                const int chunk  = task & 7;         // 4 floats each
                const int row = rowcol / XCOLS;
                const int col = rowcol - row * XCOLS;
                const int rg = h0 - 1 + row;
                const int cg = col - 1;
                f32x4 v = {0.f, 0.f, 0.f, 0.f};
                if ((unsigned)rg < 64u && (unsigned)cg < 64u)
                    v = *(const f32x4*)(x + ((size_t)((b * HH + rg) * WW + cg)) * CI
                                          + c * 32 + chunk * 4);
                const f32x4 st = *(const f32x4*)(s_style + c * 32 + chunk * 4);
                const f32x4 m = v * st;
                uint2 u;
                u.x = pk2(m.x, m.y);
                u.y = pk2(m.z, m.w);
                *(uint2*)(xs + rowcol * CIPITCH + chunk * 4) = u;
            }
        }

        #pragma unroll
        for (int tr = 0; tr < 3; ++tr) {
            if (tr) __syncthreads();   // prev tr's bs readers done

            // ---- stage bs: 128 co x 3 taps x 32 k ----
            #pragma unroll
            for (int p = 0; p < 6; ++p) {
                const int task = p * 256 + tid;      // < 1536
                const int co = task / 12;
                const int r  = task - co * 12;
                const int tl = r >> 2;
                const int ch = r & 3;
                const uint4 v = *(const uint4*)(Wt + (size_t)(n0 + co) * KTOT
                                                + (tr * 3 + tl) * 256 + c * 32 + ch * 8);
                *(uint4*)(bs + co * BPITCH + tl * 32 + ch * 8) = v;
            }
            __syncthreads();           // xs (tr==0) + bs visible

            #pragma unroll
            for (int tl = 0; tl < 3; ++tl) {
                const int t  = tr * 3 + tl;
                const int dh = t / 3;                // 0..2
                const int dw = t - dh * 3;           // 0..2

                f16x8 af[4], bf[4];
                #pragma unroll
                for (int i = 0; i < 4; ++i) {
                    const int mb   = wm + i * 16;
                    const int mrow = (mb >> 6) + dh;
                    const int mcol = (mb & 63) + dw;
                    af[i] = *(const f16x8*)(xs + (mrow * XCOLS + mcol) * CIPITCH + xlane);
                }
                #pragma unroll
                for (int j = 0; j < 4; ++j)
                    bf[j] = *(const f16x8*)(bs + (wn + j * 16 + fr) * BPITCH
                                            + tl * 32 + fq * 8);
                #pragma unroll
                for (int i = 0; i < 4; ++i)
                    #pragma unroll
                    for (int j = 0; j < 4; ++j)
                        acc[i][j] = __builtin_amdgcn_mfma_f32_16x16x32_f16(
                            af[i], bf[j], acc[i][j], 0, 0, 0);
            }
        }
    }

    // ---- epilogue: demod scale + store. D: col=lane&15, row=(lane>>4)*4+reg ----
    float sc[4];
    #pragma unroll
    for (int j = 0; j < 4; ++j)
        sc[j] = __frsqrt_rn(scale2[b * CO + n0 + wn + j * 16 + fr] + 1e-8f);
    #pragma unroll
    for (int i = 0; i < 4; ++i) {
        const int m_base = p0 + wm + i * 16 + fq * 4;
        #pragma unroll
        for (int j = 0; j < 4; ++j) {
            float* yp = y + (size_t)m_base * CO + n0 + wn + j * 16 + fr;
            #pragma unroll
            for (int r = 0; r < 4; ++r)
                yp[(size_t)r * CO] = acc[i][j][r] * sc[j];
        }
    }
}

extern "C" void kernel_launch(void* const* d_in, const int* in_sizes, int n_in,
                              void* d_out, int out_size, void* d_ws, size_t ws_size,
                              hipStream_t stream) {
    const float* x     = (const float*)d_in[0];  // [16,64,64,256]
    const float* style = (const float*)d_in[1];  // [16,256]
    const float* kern  = (const float*)d_in[2];  // [3,3,256,256]
    float* out = (float*)d_out;                  // [16,64,64,256]

    float*  scale2 = (float*)d_ws;                        // 16*256 fp32 = 16 KB
    ushort* Wt     = (ushort*)((char*)d_ws + 16384);      // [256][2304] f16

    hipMemsetAsync(scale2, 0, 16 * CO * sizeof(float), stream);
    prep<<<144, 256, 0, stream>>>(kern, style, Wt, scale2);
    gemm_conv<<<512 * 2, 256, 0, stream>>>(x, Wt, style, scale2, out);
}

// Round 5
// 225.653 us; speedup vs baseline: 1.5707x; 1.0440x over previous
//
#include <hip/hip_runtime.h>

// ModConv2D — StyleGAN2 modulated conv as implicit GEMM, f16 MFMA.
// B=16, H=W=64, CIN=COUT=256, 3x3 SAME, fp32 I/O.
//
// R9: weight path -> global_load_lds DMA pipeline (zero new VGPRs).
//   - Wt stored pre-arranged in DMA order: Wt2[c][t9][fq][co 256][8e] f16,
//     so a linear wave DMA (uniform LDS base + lane*16B) lands the (c,tap)
//     tile with conflict-free bf reads (bank = 4*fr, uniform 8 dw/bank).
//   - K-loop: 9 tap-steps/slice, bs triple-buffered (3 x 8KB). Step s issues
//     step s+2's DMA (2 lane-loads/thread); step start = s_waitcnt vmcnt(2)
//     (counted — tile issued ~2 phases earlier) + s_barrier. No phase drains
//     the load queue; the 6 full-drain syncthreads/slice are gone.
//   - bstage reg round-trip + LDS writes gone (was the bank-conflict source).
//   - xs staging identical to R5/R8 (needs VALU modulate; no reg headroom:
//     104 VGPR + 64 AGPR = 168 vs ~170 budget at 3 blocks/CU).

#define HH 64
#define WW 64
#define CI 256
#define CO 256
#define KTOT 2304
#define CIPITCH 40       // ushorts per (row,col): 32 ci + 8 pad (80 B)
#define XCOLS 66

typedef float    f32x4 __attribute__((ext_vector_type(4)));
typedef _Float16 f16x8 __attribute__((ext_vector_type(8)));
typedef __fp16   fp16x2 __attribute__((ext_vector_type(2)));

__device__ __forceinline__ unsigned pk2(float a, float b) {
    fp16x2 h = __builtin_amdgcn_cvt_pkrtz(a, b);
    return __builtin_bit_cast(unsigned, h);
}

// ---- fused prep: Wt2 in DMA order AND scale2 partial sums ----
// Wt2 ushort index: (((c*9 + t9)*4 + fq)*256 + co)*8 + e
//   where k = t9*256 + c*32 + fq*8 + e   (t9 = tap 0..8)
// scale2[b][co] = sum_{t,ci} kern[t][ci][co]^2 * (style[b][ci]+1)^2
__global__ __launch_bounds__(256) void prep(
    const float* __restrict__ kern,    // [9][CI][CO]
    const float* __restrict__ style,   // [B][CI]
    ushort* __restrict__ Wt2,          // DMA-ordered, 9*256*256 ushorts
    float* __restrict__ scale2)        // [B][CO], pre-zeroed
{
    __shared__ ushort tile[64][65];
    __shared__ float  sqt[64][65];
    __shared__ float  st2l[16][64];

    const int kt = blockIdx.x >> 2;     // 0..35
    const int ct = blockIdx.x & 3;
    const int k0 = kt * 64, c0 = ct * 64;
    const int ci0 = k0 & 255;
    const int tid = threadIdx.x;
    const int r = tid >> 2, q = tid & 3;

    // (style+1)^2 for this block's 64-ci window, all 16 samples
    #pragma unroll
    for (int p = 0; p < 4; ++p) {
        const int i = p * 256 + tid;            // 0..1023
        const int bb = i >> 6, rr = i & 63;
        const float s = style[bb * CI + ci0 + rr] + 1.0f;
        st2l[bb][rr] = s * s;
    }

    const float* src = kern + (size_t)(k0 + r) * CO + c0 + q * 16;
    #pragma unroll
    for (int j = 0; j < 16; ++j) {
        const float v = src[j];
        _Float16 h = (_Float16)v;
        tile[q * 16 + j][r] = __builtin_bit_cast(unsigned short, h);
        sqt[r][q * 16 + j] = v * v;             // fp32 squares for demod
    }
    __syncthreads();

    // scatter transposed f16 weights into DMA order
    const int co_w = c0 + r;
    #pragma unroll
    for (int j = 0; j < 16; ++j) {
        const int k   = k0 + q * 16 + j;
        const int t9  = k >> 8;
        const int rem = k & 255;
        const int cc  = rem >> 5;
        const int fq  = (rem >> 3) & 3;
        const int e   = k & 7;
        Wt2[((((size_t)cc * 9 + t9) * 4 + fq) * 256 + co_w) * 8 + e] =
            tile[r][q * 16 + j];
    }

    // reduce over the 64 ci: thread = (co = tid&63, 4 b's)
    const int co = tid & 63;
    const int bq = tid >> 6;                    // wave-uniform
    float acc[4] = {0.f, 0.f, 0.f, 0.f};
    #pragma unroll 4
    for (int rr = 0; rr < 64; ++rr) {
        const float s = sqt[rr][co];
        #pragma unroll
        for (int bb = 0; bb < 4; ++bb)
            acc[bb] += s * st2l[bq * 4 + bb][rr];   // broadcast read
    }
    #pragma unroll
    for (int bb = 0; bb < 4; ++bb)
        atomicAdd(&scale2[(bq * 4 + bb) * CO + c0 + co], acc[bb]);
}

// ---- implicit-GEMM conv ----
__global__ __launch_bounds__(256) void gemm_conv(
    const float* __restrict__ x,        // [B][H][W][CI] fp32
    const ushort* __restrict__ Wt2,     // DMA-ordered f16 weights
    const float* __restrict__ style,    // [B][CI]
    const float* __restrict__ scale2,   // [B][CO] sum-of-squares
    float* __restrict__ y)              // [B][H][W][CO] fp32
{
    __shared__ __align__(16) ushort xs[4 * XCOLS * CIPITCH];  // 21120 B
    __shared__ __align__(16) ushort bs[3 * 4096];             // 3 bufs x 8192 B
    __shared__ float s_style[CI];

    const int tid  = threadIdx.x;
    const int lane = tid & 63;
    const int wave = tid >> 6;

    const int mtile = blockIdx.x >> 1;
    const int n0    = (blockIdx.x & 1) * 128;
    const int p0    = mtile * 128;            // 2 image rows of one sample
    const int b     = p0 >> 12;
    const int h0    = (p0 >> 6) & 63;

    s_style[tid] = style[b * CI + tid] + 1.0f;

    const int wm = (wave & 1) * 64;
    const int wn = (wave >> 1) * 64;
    const int fr = lane & 15;
    const int fq = lane >> 4;
    const int xlane = fr * CIPITCH + fq * 8;   // per-lane A-frag offset

    // DMA issue for tile (cn, t9n) -> buffer bufn. 512 lane-loads of 16 B:
    // task = p*256+tid; global = Wt2[(cn*9+t9n)*4*256*8 + task*8 + n0*8];
    // LDS   = bs[bufn*4096 + task*8]  (wave-uniform base + lane*16 B).
    auto issue_tile = [&](int cn, int t9n, int bufn) {
        const ushort* gb = Wt2 + ((size_t)((cn * 9 + t9n) * 4) * 256 + n0) * 8;
        #pragma unroll
        for (int p = 0; p < 2; ++p) {
            const int task = p * 256 + tid;
            const ushort* g = gb + (size_t)(((task >> 7) << 8) + (task & 127)) * 8;
            const ushort* l = bs + bufn * 4096 + (p * 256 + (tid & ~63)) * 8;
            __builtin_amdgcn_global_load_lds(
                (const __attribute__((address_space(1))) void*)g,
                (__attribute__((address_space(3))) void*)l,
                16, 0, 0);
        }
    };

    f32x4 acc[4][4] = {};

    // prologue: tiles for steps 0 and 1
    issue_tile(0, 0, 0);
    issue_tile(0, 1, 1);

    for (int c = 0; c < 8; ++c) {
        #pragma unroll
        for (int t9 = 0; t9 < 9; ++t9) {
            // counted wait: retire this step's tile (issued 2 steps ago),
            // keep next step's 2 loads in flight. lgkm drain is ~free here.
            asm volatile("s_waitcnt vmcnt(2) lgkmcnt(0)" ::: "memory");
            __builtin_amdgcn_s_barrier();

            if (t9 == 0) {
                // ---- stage xs: 4 rows x 66 cols x 32 ci, modulated, f16 ----
                #pragma unroll
                for (int p = 0; p < 9; ++p) {
                    const int task = p * 256 + tid;
                    if (task < 2112) {
                        const int rowcol = task >> 3;        // 0..263
                        const int chunk  = task & 7;         // 4 floats each
                        const int row = rowcol / XCOLS;
                        const int col = rowcol - row * XCOLS;
                        const int rg = h0 - 1 + row;
                        const int cg = col - 1;
                        f32x4 v = {0.f, 0.f, 0.f, 0.f};
                        if ((unsigned)rg < 64u && (unsigned)cg < 64u)
                            v = *(const f32x4*)(x + ((size_t)((b * HH + rg) * WW + cg)) * CI
                                                  + c * 32 + chunk * 4);
                        const f32x4 st = *(const f32x4*)(s_style + c * 32 + chunk * 4);
                        const f32x4 m = v * st;
                        uint2 u;
                        u.x = pk2(m.x, m.y);
                        u.y = pk2(m.z, m.w);
                        *(uint2*)(xs + rowcol * CIPITCH + chunk * 4) = u;
                    }
                }
                asm volatile("s_waitcnt lgkmcnt(0)" ::: "memory");
                __builtin_amdgcn_s_barrier();   // xs visible
            }

            // issue DMA for step s+2 into buf (t9+2)%3 — its previous
            // readers (step s-1) all finished before this step's barrier.
            {
                const int tn  = t9 + 2;
                const int t9n = (tn >= 9) ? tn - 9 : tn;
                if (t9 < 7) {
                    issue_tile(c, t9n, t9n % 3);
                } else if (c < 7) {
                    issue_tile(c + 1, t9n, t9n % 3);
                }
            }

            // ---- MFMA on buffer t9%3 (tap t9) ----
            {
                const int buf = t9 % 3;
                const int dh  = t9 / 3;               // 0..2
                const int dw  = t9 - dh * 3;          // 0..2

                f16x8 af[4], bf[4];
                #pragma unroll
                for (int i = 0; i < 4; ++i) {
                    const int mb   = wm + i * 16;
                    const int mrow = (mb >> 6) + dh;
                    const int mcol = (mb & 63) + dw;
                    af[i] = *(const f16x8*)(xs + (mrow * XCOLS + mcol) * CIPITCH + xlane);
                }
                #pragma unroll
                for (int j = 0; j < 4; ++j)
                    bf[j] = *(const f16x8*)(bs + buf * 4096 + fq * 1024
                                            + (wn + j * 16 + fr) * 8);
                #pragma unroll
                for (int i = 0; i < 4; ++i)
                    #pragma unroll
                    for (int j = 0; j < 4; ++j)
                        acc[i][j] = __builtin_amdgcn_mfma_f32_16x16x32_f16(
                            af[i], bf[j], acc[i][j], 0, 0, 0);
            }
        }
    }

    // ---- epilogue: demod scale + store. D: col=lane&15, row=(lane>>4)*4+reg ----
    float sc[4];
    #pragma unroll
    for (int j = 0; j < 4; ++j)
        sc[j] = __frsqrt_rn(scale2[b * CO + n0 + wn + j * 16 + fr] + 1e-8f);
    #pragma unroll
    for (int i = 0; i < 4; ++i) {
        const int m_base = p0 + wm + i * 16 + fq * 4;
        #pragma unroll
        for (int j = 0; j < 4; ++j) {
            float* yp = y + (size_t)m_base * CO + n0 + wn + j * 16 + fr;
            #pragma unroll
            for (int r = 0; r < 4; ++r)
                yp[(size_t)r * CO] = acc[i][j][r] * sc[j];
        }
    }
}

extern "C" void kernel_launch(void* const* d_in, const int* in_sizes, int n_in,
                              void* d_out, int out_size, void* d_ws, size_t ws_size,
                              hipStream_t stream) {
    const float* x     = (const float*)d_in[0];  // [16,64,64,256]
    const float* style = (const float*)d_in[1];  // [16,256]
    const float* kern  = (const float*)d_in[2];  // [3,3,256,256]
    float* out = (float*)d_out;                  // [16,64,64,256]

    float*  scale2 = (float*)d_ws;                        // 16*256 fp32 = 16 KB
    ushort* Wt2    = (ushort*)((char*)d_ws + 16384);      // 9*256*256 f16 = 1.18 MB

    hipMemsetAsync(scale2, 0, 16 * CO * sizeof(float), stream);
    prep<<<144, 256, 0, stream>>>(kern, style, Wt2, scale2);
    gemm_conv<<<512 * 2, 256, 0, stream>>>(x, Wt2, style, scale2, out);
}